// Round 3
// baseline (342.637 us; speedup 1.0000x reference)
//
#include <hip/hip_runtime.h>

// Problem constants
#define Bq 16
#define Cq 512
#define Nq 4096
#define Hq 512

typedef float f32x4 __attribute__((ext_vector_type(4)));

// ---------------------------------------------------------------------------
// K1 (x pass 1): grid = B*16*8 = 2048 blocks: (b, nc = 256-wide n-slice,
// cq = 64-row c-eighth). Wave w handles c = cq*64 + w + 4k (k=0..15),
// lane l owns cols 4l..4l+3.
//  - column sums -> LDS cross-wave reduce -> atomicAdd xs_n[b,n]  (8 adders)
//  - row sums    -> wave shuffle reduce   -> atomicAdd xs_c[b,c]  (16 adders)
// 4 KB LDS, ~2x resident blocks vs old 1024-block version; no partial bufs.
// ---------------------------------------------------------------------------
__global__ __launch_bounds__(256) void k1_stats(const float* __restrict__ x,
                                                float* __restrict__ xs_n,
                                                float* __restrict__ xs_c){
  __shared__ float colred[4][256];
  int blk  = blockIdx.x;
  int b    = blk >> 7;
  int nc   = (blk >> 3) & 15;
  int cq   = blk & 7;
  int wave = threadIdx.x >> 6;
  int lane = threadIdx.x & 63;
  int c0   = cq*64 + wave;
  const float* p = x + ((size_t)b*Cq + c0)*Nq + (nc << 8) + (lane << 2);
  float4 acc = {0.f,0.f,0.f,0.f};
  #pragma unroll 8
  for (int k = 0; k < 16; ++k){
    float4 v = *(const float4*)(p + (size_t)(k*4)*Nq);
    acc.x += v.x; acc.y += v.y; acc.z += v.z; acc.w += v.w;
    float r = (v.x + v.y) + (v.z + v.w);
    #pragma unroll
    for (int off=32; off; off>>=1) r += __shfl_down(r, off, 64);
    if (lane == 0) atomicAdd(&xs_c[b*Cq + c0 + k*4], r);
  }
  *(float4*)&colred[wave][lane << 2] = acc;
  __syncthreads();
  int t = threadIdx.x;
  atomicAdd(&xs_n[(size_t)b*Nq + (nc << 8) + t],
            (colred[0][t] + colred[1][t]) + (colred[2][t] + colred[3][t]));
}

// ---------------------------------------------------------------------------
// K2: s_cf[b,h] = sum_n xs_n[b,n]*w_cf[h,n]   (blocks [0,512))
//     s_sf[b,h] = sum_c xs_c[b,c]*w_sf[h,c]   (blocks [512,1024))
// ---------------------------------------------------------------------------
__global__ __launch_bounds__(256) void k2_s(const float* __restrict__ w_cf,
                                            const float* __restrict__ w_sf,
                                            const float* __restrict__ xs_n,
                                            const float* __restrict__ xs_c,
                                            float* __restrict__ s_cf,
                                            float* __restrict__ s_sf){
  __shared__ float red[4][Bq];
  int blk = blockIdx.x;
  const float* w; const float* src; float* dst; int L;
  if (blk < Hq) { w = w_cf + (size_t)blk*Nq; src = xs_n; dst = s_cf; L = Nq; }
  else          { w = w_sf + (size_t)(blk-Hq)*Cq; src = xs_c; dst = s_sf; L = Cq; }
  int h = blk & (Hq-1);
  int t = threadIdx.x;
  int wave = t >> 6, lane = t & 63;
  float acc[Bq];
  #pragma unroll
  for (int b=0;b<Bq;b++) acc[b]=0.f;
  for (int i0 = t*4; i0 < L; i0 += 1024){
    float4 wv = *(const float4*)(w + i0);
    #pragma unroll
    for (int b=0;b<Bq;b++){
      float4 sv = *(const float4*)(src + (size_t)b*L + i0);
      acc[b] += wv.x*sv.x + wv.y*sv.y + wv.z*sv.z + wv.w*sv.w;
    }
  }
  #pragma unroll
  for (int b=0;b<Bq;b++){
    float v = acc[b];
    #pragma unroll
    for (int off=32; off; off>>=1) v += __shfl_down(v, off, 64);
    if (lane == 0) red[wave][b] = v;
  }
  __syncthreads();
  if (t < Bq)
    dst[(size_t)t*Hq + h] = (red[0][t]+red[1][t])+(red[2][t]+red[3][t]);
}

// ---------------------------------------------------------------------------
// K3: v_cg[b,n] = sum_h s_cf[b,h]*w_cg[h,n] ; v_sg[b,c] analogous.
// 64-h chunks x 2 batch-halves, atomicAdd directly into v_cg/v_sg
// (zeroed by the prologue memset) -- no part_* round trip.
// ---------------------------------------------------------------------------
__global__ __launch_bounds__(256) void k3_v(const float* __restrict__ w_cg,
                                            const float* __restrict__ w_sg,
                                            const float* __restrict__ s_cf,
                                            const float* __restrict__ s_sf,
                                            float* __restrict__ v_cg,
                                            float* __restrict__ v_sg){
  __shared__ float sl[8*64];
  int blk = blockIdx.x;
  const float* w; const float* s; float* dst; int L, jc, hc, bh;
  if (blk < 256){ w=w_cg; s=s_cf; dst=v_cg; L=Nq;
    jc = blk >> 4; hc = (blk >> 1) & 7; bh = blk & 1; }
  else { int k = blk - 256; w=w_sg; s=s_sf; dst=v_sg; L=Cq;
    jc = k >> 4; hc = (k >> 1) & 7; bh = k & 1; }
  int h0 = hc*64, b0 = bh*8;
  for (int i = threadIdx.x; i < 8*64; i += 256){
    int bb = i >> 6, hh = i & 63;
    sl[i] = s[(b0+bb)*Hq + h0 + hh];
  }
  __syncthreads();
  int j = (jc<<8) + (int)threadIdx.x;
  float acc[8];
  #pragma unroll
  for (int bb=0;bb<8;bb++) acc[bb]=0.f;
  #pragma unroll 8
  for (int hh=0; hh<64; ++hh){
    float wv = w[(size_t)(h0+hh)*L + j];
    #pragma unroll
    for (int bb=0;bb<8;bb++) acc[bb] += sl[bb*64+hh]*wv;
  }
  #pragma unroll
  for (int bb=0;bb<8;bb++)
    atomicAdd(&dst[(size_t)(b0+bb)*L + j], acc[bb]);
}

// ---------------------------------------------------------------------------
// K4 (x pass 2): same 2048-block tiling as K1. Preamble is just 2 direct
// loads (vs[64] slice of v_sg, float4 of v_cg). Outputs go straight to
// ch_comp[b,c] / sp_comp[b,n] via atomicAdd (zeroed in prologue).
// ---------------------------------------------------------------------------
__global__ __launch_bounds__(256) void k4_comp(const float* __restrict__ x,
                                               const float* __restrict__ v_cg,
                                               const float* __restrict__ v_sg,
                                               float* __restrict__ sp_comp,
                                               float* __restrict__ ch_comp){
  __shared__ float colred[4][256];
  __shared__ float vs[64];
  int blk  = blockIdx.x;
  int b    = blk >> 7;
  int nc   = (blk >> 3) & 15;
  int cq   = blk & 7;
  int wave = threadIdx.x >> 6;
  int lane = threadIdx.x & 63;
  int t    = threadIdx.x;
  if (t < 64) vs[t] = v_sg[b*Cq + cq*64 + t];
  float4 g = *(const float4*)(v_cg + (size_t)b*Nq + (nc << 8) + (lane << 2));
  __syncthreads();
  int c0 = cq*64 + wave;
  const float* p = x + ((size_t)b*Cq + c0)*Nq + (nc << 8) + (lane << 2);
  float4 acc = {0.f,0.f,0.f,0.f};
  #pragma unroll 8
  for (int k = 0; k < 16; ++k){
    float4 v = *(const float4*)(p + (size_t)(k*4)*Nq);
    float s = vs[wave + k*4];                       // wave-uniform broadcast
    acc.x += v.x*s; acc.y += v.y*s; acc.z += v.z*s; acc.w += v.w*s;
    float r = v.x*g.x + v.y*g.y + v.z*g.z + v.w*g.w;
    #pragma unroll
    for (int off=32; off; off>>=1) r += __shfl_down(r, off, 64);
    if (lane == 0) atomicAdd(&ch_comp[b*Cq + c0 + k*4], r);
  }
  *(float4*)&colred[wave][lane << 2] = acc;
  __syncthreads();
  atomicAdd(&sp_comp[(size_t)b*Nq + (nc << 8) + t],
            (colred[0][t] + colred[1][t]) + (colred[2][t] + colred[3][t]));
}

// ---------------------------------------------------------------------------
// K5: softmax straight off ch_comp / sp_comp (already fully reduced).
// blocks [0,16): channel (L=512); [16,32): spatial (L=4096). Masks -> out tail.
// ---------------------------------------------------------------------------
__global__ __launch_bounds__(256) void k5_softmax(const float* __restrict__ ch_comp,
                                                  const float* __restrict__ sp_comp,
                                                  float* __restrict__ out){
  __shared__ float buf[Nq];
  __shared__ float lds[4];
  __shared__ float bcast;
  int blk = blockIdx.x;
  int t = threadIdx.x;
  float* dst; int L;
  const size_t OUT0 = (size_t)Bq*Cq*Nq;
  if (blk < Bq){
    int b = blk; L = Cq;
    for (int c = t; c < Cq; c += 256) buf[c] = ch_comp[b*Cq + c];
    dst = out + OUT0 + (size_t)b*Cq;
  } else {
    int b = blk - Bq; L = Nq;
    for (int n = t; n < Nq; n += 256) buf[n] = sp_comp[(size_t)b*Nq + n];
    dst = out + OUT0 + (size_t)Bq*Cq + (size_t)b*Nq;
  }
  __syncthreads();
  float m = -3.4e38f;
  for (int i=t;i<L;i+=256) m = fmaxf(m, buf[i]);
  #pragma unroll
  for (int off=32; off; off>>=1) m = fmaxf(m, __shfl_down(m, off, 64));
  if ((t&63)==0) lds[t>>6]=m;
  __syncthreads();
  if (t==0) bcast = fmaxf(fmaxf(lds[0],lds[1]),fmaxf(lds[2],lds[3]));
  __syncthreads();
  m = bcast;
  float ssum=0.f;
  for (int i=t;i<L;i+=256) ssum += __expf(buf[i]-m);
  #pragma unroll
  for (int off=32; off; off>>=1) ssum += __shfl_down(ssum, off, 64);
  __syncthreads();
  if ((t&63)==0) lds[t>>6]=ssum;
  __syncthreads();
  if (t==0) bcast = 1.f/((lds[0]+lds[1])+(lds[2]+lds[3]));
  __syncthreads();
  float inv = bcast;
  for (int i=t;i<L;i+=256) dst[i] = __expf(buf[i]-m)*inv;
}

// ---------------------------------------------------------------------------
// K6: out[b,c,n] = x[b,c,n] * cm[b,c] * sm[b,n]. One row per block (8192),
// 4 float4 per thread; NT stores keep x L3-resident during the read stream.
// ---------------------------------------------------------------------------
__global__ __launch_bounds__(256) void k6_out(const float* __restrict__ x,
                                              float* __restrict__ out){
  const size_t OUT0 = (size_t)Bq*Cq*Nq;
  const float* cm = out + OUT0;
  const float* sm = out + OUT0 + (size_t)Bq*Cq;
  int blk = blockIdx.x;              // b*512 + c
  int b = blk >> 9;
  size_t rowoff = (size_t)blk * Nq;
  float cmv = cm[blk];
  const float* sp = sm + (size_t)b*Nq;
  int t = threadIdx.x;
  #pragma unroll
  for (int q = 0; q < 4; ++q){
    int n0 = q*1024 + t*4;
    float4 xv = *(const float4*)(x + rowoff + n0);
    float4 sv = *(const float4*)(sp + n0);
    f32x4 o;
    o.x = xv.x*cmv*sv.x; o.y = xv.y*cmv*sv.y;
    o.z = xv.z*cmv*sv.z; o.w = xv.w*cmv*sv.w;
    __builtin_nontemporal_store(o, (f32x4*)(out + rowoff + n0));
  }
}

extern "C" void kernel_launch(void* const* d_in, const int* in_sizes, int n_in,
                              void* d_out, int out_size, void* d_ws, size_t ws_size,
                              hipStream_t stream){
  const float* x    = (const float*)d_in[0];
  const float* w_cf = (const float*)d_in[1];
  const float* w_cg = (const float*)d_in[2];
  const float* w_sf = (const float*)d_in[3];
  const float* w_sg = (const float*)d_in[4];
  float* out = (float*)d_out;

  float* ws = (float*)d_ws;
  // atomic accumulators (zeroed below), laid out contiguously:
  float* xs_n    = ws;                       // B*N = 65536
  float* xs_c    = xs_n    + Bq*Nq;          // B*C =  8192
  float* v_cg    = xs_c    + Bq*Cq;          // B*N = 65536
  float* v_sg    = v_cg    + Bq*Nq;          // B*C =  8192
  float* ch_comp = v_sg    + Bq*Cq;          // B*C =  8192
  float* sp_comp = ch_comp + Bq*Cq;          // B*N = 65536
  // plain buffers (written before read, no zeroing needed):
  float* s_cf    = sp_comp + Bq*Nq;          // B*H =  8192
  float* s_sf    = s_cf    + Bq*Hq;          // B*H =  8192
  const size_t ZERO_FLOATS = (size_t)2*Bq*Nq + Bq*Nq + 3*(size_t)Bq*Cq; // 221184

  hipMemsetAsync(ws, 0, ZERO_FLOATS*sizeof(float), stream);  // ~0.9 MB, ~0.2 us
  k1_stats  <<<2048,  256, 0, stream>>>(x, xs_n, xs_c);
  k2_s      <<<2*Hq,  256, 0, stream>>>(w_cf, w_sf, xs_n, xs_c, s_cf, s_sf);
  k3_v      <<<288,   256, 0, stream>>>(w_cg, w_sg, s_cf, s_sf, v_cg, v_sg);
  k4_comp   <<<2048,  256, 0, stream>>>(x, v_cg, v_sg, sp_comp, ch_comp);
  k5_softmax<<<2*Bq,  256, 0, stream>>>(ch_comp, sp_comp, out);
  k6_out    <<<Bq*Cq, 256, 0, stream>>>(x, out);
}

// Round 5
// 328.500 us; speedup vs baseline: 1.0430x; 1.0430x over previous
//
#include <hip/hip_runtime.h>
#include <hip/hip_cooperative_groups.h>

namespace cg = cooperative_groups;

// Problem constants
#define Bq 16
#define Cq 512
#define Nq 4096
#define Hq 512

typedef float f32x4 __attribute__((ext_vector_type(4)));

// workspace float offsets (same arena scheme as the proven 7-kernel version)
#define O_XSN 0
#define O_XSC (O_XSN + Bq*Nq)             // 65536
#define O_SCF (O_XSC + Bq*Cq)             // 73728
#define O_SSF (O_SCF + Bq*Hq)             // 81920
#define O_ARA (O_SSF + Bq*Hq)             // 90112
#define O_PXN (O_ARA)                     // part_xs_n [4][B][N]   (P1 -> P2)
#define O_PXC (O_ARA + 4*Bq*Nq)           // part_xs_c [B*16][C]   (P1 -> P2)
#define O_PCG (O_ARA)                     // part_cg   [8][B][N]   (P4 -> P5)
#define O_PSG (O_ARA + 8*Bq*Nq)           // part_sg   [8][B][C]
#define O_ARB (O_ARA + 8*Bq*Nq + 8*Bq*Cq)
#define O_PSP (O_ARB)                     // part_sp   [4][B][N]   (P5 -> P6)
#define O_PCH (O_ARB + 4*Bq*Nq)          // part_ch   [B*16][C]

// ===========================================================================
// Fused cooperative kernel: 1024 blocks x 256 threads (4 blocks/CU).
// Every grid.sync is bracketed by explicit system-scope fences so normal
// stores are L2-written-back / invalidated across the 8 non-coherent XCD L2s.
// ===========================================================================
__device__ __forceinline__ void gsync(cg::grid_group& g){
  __syncthreads();
  if (threadIdx.x == 0) __threadfence_system();   // release: write back L2
  g.sync();
  if (threadIdx.x == 0) __threadfence_system();   // acquire: invalidate L2
  __syncthreads();
}

__global__ __launch_bounds__(256, 4) void fused_all(
    const float* __restrict__ x,
    const float* __restrict__ w_cf, const float* __restrict__ w_cg,
    const float* __restrict__ w_sf, const float* __restrict__ w_sg,
    float* __restrict__ out, float* __restrict__ ws)
{
  cg::grid_group grid = cg::this_grid();
  __shared__ float smem[4101];
  const int blk  = blockIdx.x;
  const int t    = threadIdx.x;
  const int wave = t >> 6;
  const int lane = t & 63;

  float* part_xs_n = ws + O_PXN;
  float* part_xs_c = ws + O_PXC;
  float* xs_n      = ws + O_XSN;
  float* xs_c      = ws + O_XSC;
  float* s_cf      = ws + O_SCF;
  float* s_sf      = ws + O_SSF;
  float* part_cg   = ws + O_PCG;
  float* part_sg   = ws + O_PSG;
  float* part_sp   = ws + O_PSP;
  float* part_ch   = ws + O_PCH;

  // ---- P1: pass 1 over x: row/col partial sums --------------------------
  {
    int b = blk >> 6, nc = (blk >> 2) & 15, cq = blk & 3;
    int c0 = cq*128 + wave;
    const float* p = x + ((size_t)b*Cq + c0)*Nq + (nc << 8) + (lane << 2);
    float* pc = part_xs_c + ((size_t)(b*16 + nc) << 9) + c0;
    float4 acc = {0.f,0.f,0.f,0.f};
    #pragma unroll 8
    for (int k = 0; k < 32; ++k){
      float4 v = *(const float4*)(p + (size_t)(k*4)*Nq);
      acc.x += v.x; acc.y += v.y; acc.z += v.z; acc.w += v.w;
      float r = (v.x + v.y) + (v.z + v.w);
      #pragma unroll
      for (int off=32; off; off>>=1) r += __shfl_down(r, off, 64);
      if (lane == 0) pc[k*4] = r;
    }
    *(float4*)&smem[(wave<<8) + (lane<<2)] = acc;
    __syncthreads();
    part_xs_n[((size_t)(cq*Bq) + b)*Nq + (nc << 8) + t] =
        (smem[t] + smem[256+t]) + (smem[512+t] + smem[768+t]);
  }
  gsync(grid);

  // ---- P2: reduce partials -> xs_n, xs_c --------------------------------
  if (blk < 256){
    int i = (blk << 8) + t;
    float a = 0.f;
    #pragma unroll
    for (int cq=0; cq<4; ++cq) a += part_xs_n[(size_t)cq*(Bq*Nq) + i];
    xs_n[i] = a;
  } else if (blk < 288){
    int j = ((blk-256) << 8) + t;
    int b = j >> 9, c = j & 511;
    float a = 0.f;
    #pragma unroll
    for (int nc=0; nc<16; ++nc) a += part_xs_c[((size_t)(b*16+nc) << 9) + c];
    xs_c[j] = a;
  }
  gsync(grid);

  // ---- P3: s_cf[b,h], s_sf[b,h] ------------------------------------------
  {
    const float* w; const float* src; float* dst; int L;
    if (blk < Hq) { w = w_cf + (size_t)blk*Nq; src = xs_n; dst = s_cf; L = Nq; }
    else          { w = w_sf + (size_t)(blk-Hq)*Cq; src = xs_c; dst = s_sf; L = Cq; }
    int h = blk & (Hq-1);
    float acc[Bq];
    #pragma unroll
    for (int b=0;b<Bq;b++) acc[b]=0.f;
    for (int i0 = t*4; i0 < L; i0 += 1024){
      float4 wv = *(const float4*)(w + i0);
      #pragma unroll
      for (int b=0;b<Bq;b++){
        float4 sv = *(const float4*)(src + (size_t)b*L + i0);
        acc[b] += wv.x*sv.x + wv.y*sv.y + wv.z*sv.z + wv.w*sv.w;
      }
    }
    float* red = smem;   // [4][16]
    #pragma unroll
    for (int b=0;b<Bq;b++){
      float v = acc[b];
      #pragma unroll
      for (int off=32; off; off>>=1) v += __shfl_down(v, off, 64);
      if (lane == 0) red[wave*Bq + b] = v;
    }
    __syncthreads();
    if (t < Bq)
      dst[(size_t)t*Hq + h] = (red[t]+red[Bq+t])+(red[2*Bq+t]+red[3*Bq+t]);
  }
  gsync(grid);

  // ---- P4: v partial products (288 active blocks) ------------------------
  if (blk < 288){
    float* sl = smem;    // [8*64]
    const float* w; const float* s; float* dst; int L, jc, hc, bh;
    if (blk < 256){ w=w_cg; s=s_cf; dst=part_cg; L=Nq;
      jc = blk >> 4; hc = (blk >> 1) & 7; bh = blk & 1; }
    else { int k = blk - 256; w=w_sg; s=s_sf; dst=part_sg; L=Cq;
      jc = k >> 4; hc = (k >> 1) & 7; bh = k & 1; }
    int h0 = hc*64, b0 = bh*8;
    for (int i = t; i < 8*64; i += 256){
      int bb = i >> 6, hh = i & 63;
      sl[i] = s[(b0+bb)*Hq + h0 + hh];
    }
    __syncthreads();
    int j = (jc<<8) + t;
    float acc[8];
    #pragma unroll
    for (int bb=0;bb<8;bb++) acc[bb]=0.f;
    #pragma unroll 8
    for (int hh=0; hh<64; ++hh){
      float wv = w[(size_t)(h0+hh)*L + j];
      #pragma unroll
      for (int bb=0;bb<8;bb++) acc[bb] += sl[bb*64+hh]*wv;
    }
    #pragma unroll
    for (int bb=0;bb<8;bb++)
      dst[((size_t)hc*Bq + (b0+bb))*L + j] = acc[bb];
  }
  gsync(grid);

  // ---- P5: pass 2 over x (inline v reduce) -------------------------------
  {
    int b = blk >> 6, nc = (blk >> 2) & 15, cq = blk & 3;
    float* colred = smem;        // [4][256]
    float* vs     = smem + 1024; // [128]
    if (t < 128){
      int c = cq*128 + t;
      float a = 0.f;
      #pragma unroll
      for (int hc=0; hc<8; ++hc) a += part_sg[((size_t)hc*Bq + b)*Cq + c];
      vs[t] = a;
    }
    float4 g = {0.f,0.f,0.f,0.f};
    {
      size_t off = (size_t)b*Nq + (nc << 8) + (lane << 2);
      #pragma unroll
      for (int hc=0; hc<8; ++hc){
        float4 pgv = *(const float4*)(part_cg + (size_t)hc*(Bq*Nq) + off);
        g.x += pgv.x; g.y += pgv.y; g.z += pgv.z; g.w += pgv.w;
      }
    }
    __syncthreads();
    int c0 = cq*128 + wave;
    const float* p = x + ((size_t)b*Cq + c0)*Nq + (nc << 8) + (lane << 2);
    float* pc = part_ch + ((size_t)(b*16 + nc) << 9) + c0;
    float4 acc = {0.f,0.f,0.f,0.f};
    #pragma unroll 8
    for (int k = 0; k < 32; ++k){
      float4 v = *(const float4*)(p + (size_t)(k*4)*Nq);
      float s = vs[wave + k*4];
      acc.x += v.x*s; acc.y += v.y*s; acc.z += v.z*s; acc.w += v.w*s;
      float r = v.x*g.x + v.y*g.y + v.z*g.z + v.w*g.w;
      #pragma unroll
      for (int off=32; off; off>>=1) r += __shfl_down(r, off, 64);
      if (lane == 0) pc[k*4] = r;
    }
    *(float4*)&colred[(wave<<8) + (lane<<2)] = acc;
    __syncthreads();
    part_sp[((size_t)(cq*Bq) + b)*Nq + (nc << 8) + t] =
        (colred[t] + colred[256+t]) + (colred[512+t] + colred[768+t]);
  }
  gsync(grid);

  // ---- P6: softmax -> masks in out tail (32 active blocks) ---------------
  if (blk < 2*Bq){
    float* buf   = smem;          // [4096]
    float* lds4  = smem + 4096;   // [4]
    float* bcast = smem + 4100;   // [1]
    float* dst; int L;
    const size_t OUT0 = (size_t)Bq*Cq*Nq;
    if (blk < Bq){
      int b = blk; L = Cq;
      for (int c = t; c < Cq; c += 256){
        float s = 0.f;
        #pragma unroll
        for (int nc=0; nc<16; ++nc) s += part_ch[((size_t)(b*16+nc) << 9) + c];
        buf[c] = s;
      }
      dst = out + OUT0 + (size_t)b*Cq;
    } else {
      int b = blk - Bq; L = Nq;
      for (int n = t; n < Nq; n += 256){
        float s = 0.f;
        #pragma unroll
        for (int cq=0; cq<4; ++cq) s += part_sp[((size_t)(cq*Bq)+b)*Nq + n];
        buf[n] = s;
      }
      dst = out + OUT0 + (size_t)Bq*Cq + (size_t)b*Nq;
    }
    __syncthreads();
    float m = -3.4e38f;
    for (int i=t;i<L;i+=256) m = fmaxf(m, buf[i]);
    #pragma unroll
    for (int off=32; off; off>>=1) m = fmaxf(m, __shfl_down(m, off, 64));
    if ((t&63)==0) lds4[t>>6]=m;
    __syncthreads();
    if (t==0) bcast[0] = fmaxf(fmaxf(lds4[0],lds4[1]),fmaxf(lds4[2],lds4[3]));
    __syncthreads();
    m = bcast[0];
    float ssum=0.f;
    for (int i=t;i<L;i+=256) ssum += __expf(buf[i]-m);
    #pragma unroll
    for (int off=32; off; off>>=1) ssum += __shfl_down(ssum, off, 64);
    __syncthreads();
    if ((t&63)==0) lds4[t>>6]=ssum;
    __syncthreads();
    if (t==0) bcast[0] = 1.f/((lds4[0]+lds4[1])+(lds4[2]+lds4[3]));
    __syncthreads();
    float inv = bcast[0];
    for (int i=t;i<L;i+=256) dst[i] = __expf(buf[i]-m)*inv;
  }
  gsync(grid);

  // ---- P7: out = x*cm*sm (8 rows/block, sm held in regs) -----------------
  {
    const size_t OUT0 = (size_t)Bq*Cq*Nq;
    const float* cm = out + OUT0;
    const float* smk = out + OUT0 + (size_t)Bq*Cq;
    int b = blk >> 6;
    int cbase = (blk & 63) * 8;
    const float* sp = smk + (size_t)b*Nq;
    int n0 = t*4;
    float4 sv0 = *(const float4*)(sp + n0);
    float4 sv1 = *(const float4*)(sp + n0 + 1024);
    float4 sv2 = *(const float4*)(sp + n0 + 2048);
    float4 sv3 = *(const float4*)(sp + n0 + 3072);
    #pragma unroll
    for (int r = 0; r < 8; ++r){
      int c = cbase + r;
      size_t ro = ((size_t)b*Cq + c)*Nq;
      float cmv = cm[b*Cq + c];
      float4 xv; f32x4 o;
      xv = *(const float4*)(x + ro + n0);
      o.x=xv.x*cmv*sv0.x; o.y=xv.y*cmv*sv0.y; o.z=xv.z*cmv*sv0.z; o.w=xv.w*cmv*sv0.w;
      __builtin_nontemporal_store(o, (f32x4*)(out + ro + n0));
      xv = *(const float4*)(x + ro + n0 + 1024);
      o.x=xv.x*cmv*sv1.x; o.y=xv.y*cmv*sv1.y; o.z=xv.z*cmv*sv1.z; o.w=xv.w*cmv*sv1.w;
      __builtin_nontemporal_store(o, (f32x4*)(out + ro + n0 + 1024));
      xv = *(const float4*)(x + ro + n0 + 2048);
      o.x=xv.x*cmv*sv2.x; o.y=xv.y*cmv*sv2.y; o.z=xv.z*cmv*sv2.z; o.w=xv.w*cmv*sv2.w;
      __builtin_nontemporal_store(o, (f32x4*)(out + ro + n0 + 2048));
      xv = *(const float4*)(x + ro + n0 + 3072);
      o.x=xv.x*cmv*sv3.x; o.y=xv.y*cmv*sv3.y; o.z=xv.z*cmv*sv3.z; o.w=xv.w*cmv*sv3.w;
      __builtin_nontemporal_store(o, (f32x4*)(out + ro + n0 + 3072));
    }
  }
}

// ===========================================================================
// Fallback chain — verbatim the Round-2 PASSING kernels (328 us).
// ===========================================================================
__global__ __launch_bounds__(256) void fb_k1(const float* __restrict__ x,
                                             float* __restrict__ part_xs_n,
                                             float* __restrict__ part_xs_c){
  __shared__ float colred[4][256];
  __shared__ float rowp[4][32][64];
  int blk  = blockIdx.x;
  int b    = blk >> 6;
  int nc   = (blk >> 2) & 15;
  int cq   = blk & 3;
  int wave = threadIdx.x >> 6;
  int lane = threadIdx.x & 63;
  int c0   = cq*128 + wave;
  const float* p = x + ((size_t)b*Cq + c0)*Nq + (nc << 8) + (lane << 2);
  float4 acc = {0.f,0.f,0.f,0.f};
  #pragma unroll 8
  for (int k = 0; k < 32; ++k){
    float4 v = *(const float4*)(p + (size_t)(k*4)*Nq);
    acc.x += v.x; acc.y += v.y; acc.z += v.z; acc.w += v.w;
    rowp[wave][k][lane] = (v.x + v.y) + (v.z + v.w);
  }
  *(float4*)&colred[wave][lane << 2] = acc;
  __syncthreads();
  int t = threadIdx.x;
  part_xs_n[((size_t)(cq*Bq) + b)*Nq + (nc << 8) + t] =
      (colred[0][t] + colred[1][t]) + (colred[2][t] + colred[3][t]);
  if (t < 128){
    const float4* rp4 = (const float4*)&rowp[t & 3][t >> 2][0];
    float4 sv = {0.f,0.f,0.f,0.f};
    #pragma unroll
    for (int j4 = 0; j4 < 16; ++j4){
      float4 vv = rp4[(j4 + t) & 15];
      sv.x += vv.x; sv.y += vv.y; sv.z += vv.z; sv.w += vv.w;
    }
    part_xs_c[((size_t)(b*16 + nc) << 9) + cq*128 + t] =
        (sv.x + sv.y) + (sv.z + sv.w);
  }
}

__global__ __launch_bounds__(256) void fb_k1b(const float* __restrict__ part_xs_n,
                                              const float* __restrict__ part_xs_c,
                                              float* __restrict__ xs_n,
                                              float* __restrict__ xs_c){
  int blk = blockIdx.x;
  if (blk < 256){
    int i = (blk << 8) + (int)threadIdx.x;
    float acc = 0.f;
    #pragma unroll
    for (int cq=0; cq<4; ++cq) acc += part_xs_n[(size_t)cq*(Bq*Nq) + i];
    xs_n[i] = acc;
  } else {
    int j = ((blk-256) << 8) + (int)threadIdx.x;
    int b = j >> 9, c = j & 511;
    float acc = 0.f;
    #pragma unroll
    for (int nc=0; nc<16; ++nc) acc += part_xs_c[((size_t)(b*16+nc) << 9) + c];
    xs_c[j] = acc;
  }
}

__global__ __launch_bounds__(256) void fb_k2(const float* __restrict__ w_cf,
                                             const float* __restrict__ w_sf,
                                             const float* __restrict__ xs_n,
                                             const float* __restrict__ xs_c,
                                             float* __restrict__ s_cf,
                                             float* __restrict__ s_sf){
  __shared__ float red[4][Bq];
  int blk = blockIdx.x;
  const float* w; const float* src; float* dst; int L;
  if (blk < Hq) { w = w_cf + (size_t)blk*Nq; src = xs_n; dst = s_cf; L = Nq; }
  else          { w = w_sf + (size_t)(blk-Hq)*Cq; src = xs_c; dst = s_sf; L = Cq; }
  int h = blk & (Hq-1);
  int t = threadIdx.x;
  int wave = t >> 6, lane = t & 63;
  float acc[Bq];
  #pragma unroll
  for (int b=0;b<Bq;b++) acc[b]=0.f;
  for (int i0 = t*4; i0 < L; i0 += 1024){
    float4 wv = *(const float4*)(w + i0);
    #pragma unroll
    for (int b=0;b<Bq;b++){
      float4 sv = *(const float4*)(src + (size_t)b*L + i0);
      acc[b] += wv.x*sv.x + wv.y*sv.y + wv.z*sv.z + wv.w*sv.w;
    }
  }
  #pragma unroll
  for (int b=0;b<Bq;b++){
    float v = acc[b];
    #pragma unroll
    for (int off=32; off; off>>=1) v += __shfl_down(v, off, 64);
    if (lane == 0) red[wave][b] = v;
  }
  __syncthreads();
  if (t < Bq)
    dst[(size_t)t*Hq + h] = (red[0][t]+red[1][t])+(red[2][t]+red[3][t]);
}

__global__ __launch_bounds__(256) void fb_k3(const float* __restrict__ w_cg,
                                             const float* __restrict__ w_sg,
                                             const float* __restrict__ s_cf,
                                             const float* __restrict__ s_sf,
                                             float* __restrict__ part_cg,
                                             float* __restrict__ part_sg){
  __shared__ float sl[8*64];
  int blk = blockIdx.x;
  const float* w; const float* s; float* dst; int L, jc, hc, bh;
  if (blk < 256){ w=w_cg; s=s_cf; dst=part_cg; L=Nq;
    jc = blk >> 4; hc = (blk >> 1) & 7; bh = blk & 1; }
  else { int k = blk - 256; w=w_sg; s=s_sf; dst=part_sg; L=Cq;
    jc = k >> 4; hc = (k >> 1) & 7; bh = k & 1; }
  int h0 = hc*64, b0 = bh*8;
  for (int i = threadIdx.x; i < 8*64; i += 256){
    int bb = i >> 6, hh = i & 63;
    sl[i] = s[(b0+bb)*Hq + h0 + hh];
  }
  __syncthreads();
  int j = (jc<<8) + (int)threadIdx.x;
  float acc[8];
  #pragma unroll
  for (int bb=0;bb<8;bb++) acc[bb]=0.f;
  #pragma unroll 8
  for (int hh=0; hh<64; ++hh){
    float wv = w[(size_t)(h0+hh)*L + j];
    #pragma unroll
    for (int bb=0;bb<8;bb++) acc[bb] += sl[bb*64+hh]*wv;
  }
  #pragma unroll
  for (int bb=0;bb<8;bb++)
    dst[((size_t)hc*Bq + (b0+bb))*L + j] = acc[bb];
}

__global__ __launch_bounds__(256) void fb_k4(const float* __restrict__ x,
                                             const float* __restrict__ part_cg,
                                             const float* __restrict__ part_sg,
                                             float* __restrict__ part_sp,
                                             float* __restrict__ part_ch){
  __shared__ float colred[4][256];
  __shared__ float rowp[4][32][64];
  __shared__ float vs[128];
  int blk  = blockIdx.x;
  int b    = blk >> 6;
  int nc   = (blk >> 2) & 15;
  int cq   = blk & 3;
  int wave = threadIdx.x >> 6;
  int lane = threadIdx.x & 63;
  int t    = threadIdx.x;
  if (t < 128){
    int c = cq*128 + t;
    float a = 0.f;
    #pragma unroll
    for (int hc=0; hc<8; ++hc) a += part_sg[((size_t)hc*Bq + b)*Cq + c];
    vs[t] = a;
  }
  float4 g = {0.f,0.f,0.f,0.f};
  {
    size_t off = (size_t)b*Nq + (nc << 8) + (lane << 2);
    #pragma unroll
    for (int hc=0; hc<8; ++hc){
      float4 pgv = *(const float4*)(part_cg + (size_t)hc*(Bq*Nq) + off);
      g.x += pgv.x; g.y += pgv.y; g.z += pgv.z; g.w += pgv.w;
    }
  }
  __syncthreads();
  int c0 = cq*128 + wave;
  const float* p = x + ((size_t)b*Cq + c0)*Nq + (nc << 8) + (lane << 2);
  float4 acc = {0.f,0.f,0.f,0.f};
  #pragma unroll 8
  for (int k = 0; k < 32; ++k){
    float4 v = *(const float4*)(p + (size_t)(k*4)*Nq);
    float s = vs[wave + k*4];
    acc.x += v.x*s; acc.y += v.y*s; acc.z += v.z*s; acc.w += v.w*s;
    rowp[wave][k][lane] = v.x*g.x + v.y*g.y + v.z*g.z + v.w*g.w;
  }
  *(float4*)&colred[wave][lane << 2] = acc;
  __syncthreads();
  part_sp[((size_t)(cq*Bq) + b)*Nq + (nc << 8) + t] =
      (colred[0][t] + colred[1][t]) + (colred[2][t] + colred[3][t]);
  if (t < 128){
    const float4* rp4 = (const float4*)&rowp[t & 3][t >> 2][0];
    float4 sv = {0.f,0.f,0.f,0.f};
    #pragma unroll
    for (int j4 = 0; j4 < 16; ++j4){
      float4 vv = rp4[(j4 + t) & 15];
      sv.x += vv.x; sv.y += vv.y; sv.z += vv.z; sv.w += vv.w;
    }
    part_ch[((size_t)(b*16 + nc) << 9) + cq*128 + t] =
        (sv.x + sv.y) + (sv.z + sv.w);
  }
}

__global__ __launch_bounds__(256) void fb_k5(const float* __restrict__ part_ch,
                                             const float* __restrict__ part_sp,
                                             float* __restrict__ out){
  __shared__ float buf[Nq];
  __shared__ float lds[4];
  __shared__ float bcast;
  int blk = blockIdx.x;
  int t = threadIdx.x;
  float* dst; int L;
  const size_t OUT0 = (size_t)Bq*Cq*Nq;
  if (blk < Bq){
    int b = blk; L = Cq;
    for (int c = t; c < Cq; c += 256){
      float s = 0.f;
      #pragma unroll
      for (int nc=0; nc<16; ++nc) s += part_ch[((size_t)(b*16+nc) << 9) + c];
      buf[c] = s;
    }
    dst = out + OUT0 + (size_t)b*Cq;
  } else {
    int b = blk - Bq; L = Nq;
    for (int n = t; n < Nq; n += 256){
      float s = 0.f;
      #pragma unroll
      for (int cq=0; cq<4; ++cq) s += part_sp[((size_t)(cq*Bq)+b)*Nq + n];
      buf[n] = s;
    }
    dst = out + OUT0 + (size_t)Bq*Cq + (size_t)b*Nq;
  }
  __syncthreads();
  float m = -3.4e38f;
  for (int i=t;i<L;i+=256) m = fmaxf(m, buf[i]);
  #pragma unroll
  for (int off=32; off; off>>=1) m = fmaxf(m, __shfl_down(m, off, 64));
  if ((t&63)==0) lds[t>>6]=m;
  __syncthreads();
  if (t==0) bcast = fmaxf(fmaxf(lds[0],lds[1]),fmaxf(lds[2],lds[3]));
  __syncthreads();
  m = bcast;
  float ssum=0.f;
  for (int i=t;i<L;i+=256) ssum += __expf(buf[i]-m);
  #pragma unroll
  for (int off=32; off; off>>=1) ssum += __shfl_down(ssum, off, 64);
  __syncthreads();
  if ((t&63)==0) lds[t>>6]=ssum;
  __syncthreads();
  if (t==0) bcast = 1.f/((lds[0]+lds[1])+(lds[2]+lds[3]));
  __syncthreads();
  float inv = bcast;
  for (int i=t;i<L;i+=256) dst[i] = __expf(buf[i]-m)*inv;
}

__global__ __launch_bounds__(256) void fb_k6(const float* __restrict__ x,
                                             float* __restrict__ out){
  const size_t OUT0 = (size_t)Bq*Cq*Nq;
  const float* cm = out + OUT0;
  const float* sm = out + OUT0 + (size_t)Bq*Cq;
  int blk = blockIdx.x;
  int b = blk >> 9;
  size_t rowoff = (size_t)blk * Nq;
  float cmv = cm[blk];
  const float* sp = sm + (size_t)b*Nq;
  int t = threadIdx.x;
  #pragma unroll
  for (int q = 0; q < 4; ++q){
    int n0 = q*1024 + t*4;
    float4 xv = *(const float4*)(x + rowoff + n0);
    float4 sv = *(const float4*)(sp + n0);
    f32x4 o;
    o.x = xv.x*cmv*sv.x; o.y = xv.y*cmv*sv.y;
    o.z = xv.z*cmv*sv.z; o.w = xv.w*cmv*sv.w;
    __builtin_nontemporal_store(o, (f32x4*)(out + rowoff + n0));
  }
}

extern "C" void kernel_launch(void* const* d_in, const int* in_sizes, int n_in,
                              void* d_out, int out_size, void* d_ws, size_t ws_size,
                              hipStream_t stream){
  const float* x    = (const float*)d_in[0];
  const float* w_cf = (const float*)d_in[1];
  const float* w_cg = (const float*)d_in[2];
  const float* w_sf = (const float*)d_in[3];
  const float* w_sg = (const float*)d_in[4];
  float* out = (float*)d_out;
  float* ws  = (float*)d_ws;

  // Gate the cooperative path on actual achievable occupancy (4 blocks/CU
  // needed for 1024 co-resident blocks on 256 CUs). Query is host-side and
  // capture-safe; avoids poisoning stream capture with a failing launch.
  int maxB = 0;
  hipError_t qerr = hipOccupancyMaxActiveBlocksPerMultiprocessor(
      &maxB, fused_all, 256, 0);
  if (qerr == hipSuccess && maxB >= 4){
    void* args[] = { (void*)&x, (void*)&w_cf, (void*)&w_cg,
                     (void*)&w_sf, (void*)&w_sg, (void*)&out, (void*)&ws };
    hipError_t lerr = hipLaunchCooperativeKernel((void*)fused_all, dim3(1024),
                                                 dim3(256), args, 0, stream);
    if (lerr == hipSuccess) return;
  }

  // Fallback: proven 7-kernel chain (Round-2, 328 us, passing).
  float* xs_n      = ws + O_XSN;
  float* xs_c      = ws + O_XSC;
  float* s_cf      = ws + O_SCF;
  float* s_sf      = ws + O_SSF;
  float* part_xs_n = ws + O_PXN;
  float* part_xs_c = ws + O_PXC;
  float* part_cg   = ws + O_PCG;
  float* part_sg   = ws + O_PSG;
  float* part_sp   = ws + O_PSP;
  float* part_ch   = ws + O_PCH;

  fb_k1 <<<1024,  256, 0, stream>>>(x, part_xs_n, part_xs_c);
  fb_k1b<<<288,   256, 0, stream>>>(part_xs_n, part_xs_c, xs_n, xs_c);
  fb_k2 <<<2*Hq,  256, 0, stream>>>(w_cf, w_sf, xs_n, xs_c, s_cf, s_sf);
  fb_k3 <<<288,   256, 0, stream>>>(w_cg, w_sg, s_cf, s_sf, part_cg, part_sg);
  fb_k4 <<<1024,  256, 0, stream>>>(x, part_cg, part_sg, part_sp, part_ch);
  fb_k5 <<<2*Bq,  256, 0, stream>>>(part_ch, part_sp, out);
  fb_k6 <<<Bq*Cq, 256, 0, stream>>>(x, out);
}